// Round 2
// baseline (513.515 us; speedup 1.0000x reference)
//
#include <hip/hip_runtime.h>
#include <hip/hip_bf16.h>

// Problem constants
#define BB 4
#define NN 50000
#define DIN 128
#define DOUT 128
#define EE 800000
#define TOTROWS (BB * NN)   // 200000
#define LDA 136             // padded LDS row stride (u16): 272B = 17*16B

#define NGB ((TOTROWS + 127) / 128)        // 1563 gemm blocks
#define NHB ((EE + 255) / 256)             // 3125 hist/scatter blocks
#define NPB 64                             // prep blocks (64*256 == 128*128)
#define SCHUNK 196                         // scan elems/thread (196*256 >= NN)

typedef unsigned short u16;
typedef unsigned int u32;

using shortx8 = __attribute__((ext_vector_type(8))) short;
using ushortx4 = __attribute__((ext_vector_type(4))) unsigned short;
using ushortx8 = __attribute__((ext_vector_type(8))) unsigned short;
using floatx4 = __attribute__((ext_vector_type(4))) float;

__device__ __forceinline__ float b2f(u16 u) {
    u32 x = ((u32)u) << 16;
    float f;
    __builtin_memcpy(&f, &x, 4);
    return f;
}

__device__ __forceinline__ u16 f2b(float f) {
    u32 x;
    __builtin_memcpy(&x, &f, 4);
    u32 r = x + 0x7fffu + ((x >> 16) & 1u);   // RNE
    return (u16)(r >> 16);
}

// ---------------------------------------------------------------------------
// K1: block 0 = dtype detector; blocks 1.. = degree histogram.
// flags[i] = 1 if fp32-stored, 0 if bf16-stored.
// ---------------------------------------------------------------------------
__global__ __launch_bounds__(256)
void k1_detect_hist(const u16* __restrict__ X, const u16* __restrict__ W,
                    const u16* __restrict__ Bs, const u16* __restrict__ V,
                    int nx, int nw, int nb, int nv, int* __restrict__ flags,
                    const int* __restrict__ rows, int* __restrict__ deg) {
    if (blockIdx.x == 0) {
        __shared__ int cnt[4];
        const int t = threadIdx.x;
        const int w = t >> 6;
        const int l = t & 63;
        if (t < 4) cnt[t] = 0;
        __syncthreads();
        const u16* p = (w == 0) ? X : (w == 1) ? W : (w == 2) ? Bs : V;
        const int n  = (w == 0) ? nx : (w == 1) ? nw : (w == 2) ? nb : nv;
        int bad = 0;
        for (int k = 0; k < 4; ++k) {
            unsigned idx = 2u * (unsigned)(((unsigned long long)(l * 4 + k) *
                                            (unsigned)(n >> 1)) >> 8);
            u16 s = p[idx];
            unsigned e = (s >> 7) & 0xFF;
            bool ok = ((s & 0x7FFF) == 0) || (e >= 90 && e <= 141);
            bad += ok ? 0 : 1;
        }
        atomicAdd(&cnt[w], bad);
        __syncthreads();
        if (l == 0) flags[w] = (cnt[w] >= 77) ? 1 : 0;   // >=30% implausible
    } else {
        int e = (int)(blockIdx.x - 1) * 256 + threadIdx.x;
        if (e < EE) atomicAdd(&deg[rows[e]], 1);
    }
}

// ---------------------------------------------------------------------------
// K2: block 0 = full single-workgroup exclusive scan deg -> off (raw degrees,
//     no padding); blocks 1..NPB = Wt[f*128+k] = bf16(W[k*128+f]).
// ---------------------------------------------------------------------------
__global__ __launch_bounds__(256)
void k2_scan_prep(const int* __restrict__ deg, int* __restrict__ off,
                  const void* __restrict__ Wv, const int* __restrict__ flags,
                  u16* __restrict__ Wt) {
    if (blockIdx.x == 0) {
        __shared__ int sh[256];
        const int t = threadIdx.x;
        const int c0 = t * SCHUNK;
        int s = 0;
        for (int i = 0; i < SCHUNK; ++i) {
            int idx = c0 + i;
            if (idx < NN) s += deg[idx];
        }
        sh[t] = s;
        __syncthreads();
        for (int d = 1; d < 256; d <<= 1) {
            int x = (t >= d) ? sh[t - d] : 0;
            __syncthreads();
            sh[t] += x;
            __syncthreads();
        }
        int run = (t > 0) ? sh[t - 1] : 0;
        for (int i = 0; i < SCHUNK; ++i) {
            int idx = c0 + i;
            if (idx < NN) {
                off[idx] = run;
                run += deg[idx];
            }
        }
        if (t == 255) off[NN] = sh[255];   // == E
    } else {
        int t = (int)(blockIdx.x - 1) * 256 + threadIdx.x;
        if (t < DIN * DOUT) {
            int f = t >> 7, k = t & 127;
            size_t src = (size_t)k * DOUT + f;
            Wt[t] = flags[1] ? f2b(((const float*)Wv)[src]) : ((const u16*)Wv)[src];
        }
    }
}

// ---------------------------------------------------------------------------
// K5: blocks 0..NHB-1 = edge scatter into CSR (runs first, hides under gemm);
//     blocks NHB..    = GEMM sup[(n*B+b)*128+f] = bf16(X[b*N+n,:] @ W).
// sup stores are nontemporal (consumed next kernel; don't pollute L2).
// ---------------------------------------------------------------------------
__global__ __launch_bounds__(256, 3)
void k5_scatter_gemm(const void* __restrict__ Xv, const u16* __restrict__ Wt,
                     const int* __restrict__ flags, u16* __restrict__ sup,
                     const int* __restrict__ rows, const int* __restrict__ cols,
                     const void* __restrict__ valsv, const int* __restrict__ off,
                     int* __restrict__ cur, int2* __restrict__ epk) {
    if (blockIdx.x < NHB) {
        // ---- scatter branch (no syncthreads before this return) ----
        int e = (int)blockIdx.x * 256 + threadIdx.x;
        if (e < EE) {
            int vf32 = flags[3];
            float v = vf32 ? ((const float*)valsv)[e]
                           : b2f(((const u16*)valsv)[e]);
            int r = rows[e];
            int p = off[r] + atomicAdd(&cur[r], 1);
            epk[p] = make_int2(cols[e], __float_as_int(v));
        }
        return;
    }

    // ---- GEMM branch ----
    __shared__ u16 lA[128 * LDA];   // 34 KB

    const int xf32 = flags[0];
    const int tid = threadIdx.x;
    const int wid = tid >> 6;
    const int l   = tid & 63;
    const long rowBase = (long)(blockIdx.x - NHB) * 128;

    if (xf32) {
        const float* Xf = (const float*)Xv;
#pragma unroll
        for (int i = 0; i < 16; ++i) {
            int elem = i * 1024 + tid * 4;   // row*128 + col
            int row = elem >> 7, col = elem & 127;
            long gRow = rowBase + row;
            ushortx4 w4 = (ushortx4){0, 0, 0, 0};
            if (gRow < TOTROWS) {
                float4 v = *(const float4*)(Xf + gRow * DIN + col);
                w4[0] = f2b(v.x); w4[1] = f2b(v.y);
                w4[2] = f2b(v.z); w4[3] = f2b(v.w);
            }
            *(ushortx4*)&lA[row * LDA + col] = w4;
        }
    } else {
        const u16* X16 = (const u16*)Xv;
#pragma unroll
        for (int i = 0; i < 8; ++i) {
            int elem = i * 2048 + tid * 8;
            int row = elem >> 7, col = elem & 127;
            long gRow = rowBase + row;
            ushortx8 w8 = (ushortx8){0, 0, 0, 0, 0, 0, 0, 0};
            if (gRow < TOTROWS)
                w8 = *(const ushortx8*)(X16 + gRow * DIN + col);
            *(ushortx8*)&lA[row * LDA + col] = w8;
        }
    }

    const int wx = wid & 1;        // col half
    const int wy = wid >> 1;       // row half
    const int q8 = (l >> 4) * 8;   // k sub-offset
    const int lm = l & 15;

    shortx8 bf[16];
#pragma unroll
    for (int nt = 0; nt < 4; ++nt) {
        const size_t Frow = (size_t)(wx * 64 + nt * 16 + lm) * DIN;
#pragma unroll
        for (int c = 0; c < 4; ++c)
            bf[nt * 4 + c] = *(const shortx8*)(Wt + Frow + 32 * c + q8);
    }

    floatx4 acc[4][4];
#pragma unroll
    for (int mt = 0; mt < 4; ++mt)
#pragma unroll
        for (int nt = 0; nt < 4; ++nt)
            acc[mt][nt] = (floatx4){0.f, 0.f, 0.f, 0.f};

    __syncthreads();

    for (int c = 0; c < 4; ++c) {
        shortx8 af[4];
#pragma unroll
        for (int mt = 0; mt < 4; ++mt)
            af[mt] = *(const shortx8*)
                &lA[(size_t)(wy * 64 + mt * 16 + lm) * LDA + 32 * c + q8];
#pragma unroll
        for (int mt = 0; mt < 4; ++mt)
#pragma unroll
            for (int nt = 0; nt < 4; ++nt)
                acc[mt][nt] = __builtin_amdgcn_mfma_f32_16x16x32_bf16(
                    af[mt], bf[nt * 4 + c], acc[mt][nt], 0, 0, 0);
    }

    __syncthreads();   // all A-frag reads complete before overwrite
#pragma unroll
    for (int mt = 0; mt < 4; ++mt) {
#pragma unroll
        for (int reg = 0; reg < 4; ++reg) {
            int row = wy * 64 + mt * 16 + (l >> 4) * 4 + reg;
#pragma unroll
            for (int nt = 0; nt < 4; ++nt)
                lA[row * LDA + wx * 64 + nt * 16 + lm] = f2b(acc[mt][nt][reg]);
        }
    }
    __syncthreads();

#pragma unroll
    for (int i = 0; i < 8; ++i) {
        int elem = i * 2048 + tid * 8;
        int row = elem >> 7, col = elem & 127;
        long R = rowBase + row;
        if (R < TOTROWS) {
            int b = (int)(R / NN);
            int n = (int)(R % NN);
            ushortx8 v = *(const ushortx8*)&lA[row * LDA + col];
            __builtin_nontemporal_store(
                v, (ushortx8*)(sup + ((size_t)n * BB + b) * DOUT + col));
        }
    }
}

// ---------------------------------------------------------------------------
// K6: aggregation. One wave per node; lane covers (b = l>>4, f = (l&15)*8+t).
// Per 64-descriptor chunk: coalesced load, bitonic col-sort across the wave
// (sentinel 0x7FFFFFFF pads sort to the end), then groups of 16 gathers.
// Sorting makes concurrently-resident waves sweep col-space in the same
// order -> smaller in-flight gather footprint -> better L2 hit rate.
// out stores are nontemporal so the 100MB write stream doesn't evict sup.
// ---------------------------------------------------------------------------
__global__ __launch_bounds__(256)
void k_agg(const u16* __restrict__ sup, const int* __restrict__ off,
           const int2* __restrict__ epk, const void* __restrict__ biasv,
           const int* __restrict__ flags, float* __restrict__ out) {
    const int wid = threadIdx.x >> 6;
    const int l   = threadIdx.x & 63;
    const int n = blockIdx.x * 4 + wid;
    if (n >= NN) return;

    const int p0 = __builtin_amdgcn_readfirstlane(off[n]);
    const int p1 = __builtin_amdgcn_readfirstlane(off[n + 1]);

    float acc[8] = {0.f, 0.f, 0.f, 0.f, 0.f, 0.f, 0.f, 0.f};
    const int b  = l >> 4;
    const int f0 = (l & 15) * 8;
    const int lofs = l * 8;   // == b*128 + f0 in [n][b][f] layout

    for (int pb = p0; pb < p1; pb += 64) {
        const int cnt = min(64, p1 - pb);
        int x = 0x7FFFFFFF;   // sentinel col sorts to the end
        int y = 0;            // val 0 -> contributes nothing
        if (l < cnt) {
            long long d = __builtin_nontemporal_load(
                (const long long*)(epk + pb + l));
            x = (int)(d & 0xFFFFFFFFLL);
            y = (int)(d >> 32);
        }
        // Bitonic sort ascending by col across the 64 lanes (pairs move
        // together; ties never swap so (col,val) stay associated).
#pragma unroll
        for (int k = 2; k <= 64; k <<= 1) {
#pragma unroll
            for (int j = k >> 1; j > 0; j >>= 1) {
                int px = __shfl_xor(x, j);
                int py = __shfl_xor(y, j);
                bool keepMin = ((l & k) == 0) == ((l & j) == 0);
                bool take = keepMin ? (px < x) : (px > x);
                x = take ? px : x;
                y = take ? py : y;
            }
        }
        const int cnt16 = (cnt + 15) & ~15;
        for (int j = 0; j < cnt16; j += 16) {
            int   cs[16];
            float vs[16];
#pragma unroll
            for (int q = 0; q < 16; ++q) {
                int c = __builtin_amdgcn_readlane(x, j + q);
                cs[q] = (c == 0x7FFFFFFF) ? 0 : c;   // clamp sentinel (val=0)
                vs[q] = __int_as_float(__builtin_amdgcn_readlane(y, j + q));
            }
            ushortx8 sv[16];
#pragma unroll
            for (int q = 0; q < 16; ++q)
                sv[q] = *(const ushortx8*)(sup + (size_t)cs[q] * 512 + lofs);
#pragma unroll
            for (int q = 0; q < 16; ++q)
#pragma unroll
                for (int t = 0; t < 8; ++t)
                    acc[t] += vs[q] * b2f(sv[q][t]);
        }
    }

    float bb[8];
    if (flags[2]) {
        float4 bv1 = *(const float4*)((const float*)biasv + f0);
        float4 bv2 = *(const float4*)((const float*)biasv + f0 + 4);
        bb[0] = bv1.x; bb[1] = bv1.y; bb[2] = bv1.z; bb[3] = bv1.w;
        bb[4] = bv2.x; bb[5] = bv2.y; bb[6] = bv2.z; bb[7] = bv2.w;
    } else {
        ushortx8 bv = *(const ushortx8*)((const u16*)biasv + f0);
#pragma unroll
        for (int t = 0; t < 8; ++t) bb[t] = b2f(bv[t]);
    }

    floatx4 r0, r1;
#pragma unroll
    for (int t = 0; t < 4; ++t) r0[t] = fmaxf(acc[t] + bb[t], 0.f);
#pragma unroll
    for (int t = 0; t < 4; ++t) r1[t] = fmaxf(acc[t + 4] + bb[t + 4], 0.f);

    float* op = out + ((size_t)b * NN + n) * DOUT + f0;
    __builtin_nontemporal_store(r0, (floatx4*)op);
    __builtin_nontemporal_store(r1, (floatx4*)(op + 4));
}

// ---------------------------------------------------------------------------
extern "C" void kernel_launch(void* const* d_in, const int* in_sizes, int n_in,
                              void* d_out, int out_size, void* d_ws, size_t ws_size,
                              hipStream_t stream) {
    const void* X    = d_in[0];
    const void* W    = d_in[1];
    const void* bias = d_in[2];
    const void* vals = d_in[3];
    const int* rows  = (const int*)d_in[4];
    const int* cols  = (const int*)d_in[5];
    float* out = (float*)d_out;

    char* base = (char*)d_ws;
    size_t o = 0;
    int* flags = (int*)(base + o); o += 64;
    int* deg = (int*)(base + o); o += (size_t)NN * 4;
    int* cur = (int*)(base + o); o += (size_t)NN * 4;    // deg+cur contiguous
    o = (o + 255) & ~(size_t)255;
    u16* Wt = (u16*)(base + o); o += (size_t)DIN * DOUT * 2;
    o = (o + 255) & ~(size_t)255;
    int* off = (int*)(base + o); o += (size_t)(NN + 1) * 4;
    o = (o + 255) & ~(size_t)255;
    int2* epk = (int2*)(base + o); o += (size_t)EE * 8;
    o = (o + 255) & ~(size_t)255;
    u16* sup = (u16*)(base + o); o += (size_t)BB * NN * DOUT * 2;
    (void)ws_size;

    hipMemsetAsync(deg, 0, (size_t)2 * NN * 4, stream);      // deg + cur

    k1_detect_hist<<<1 + NHB, 256, 0, stream>>>(
        (const u16*)X, (const u16*)W, (const u16*)bias, (const u16*)vals,
        in_sizes[0], in_sizes[1], in_sizes[2], in_sizes[3], flags, rows, deg);
    k2_scan_prep<<<1 + NPB, 256, 0, stream>>>(deg, off, W, flags, Wt);
    k5_scatter_gemm<<<NHB + NGB, 256, 0, stream>>>(
        X, Wt, flags, sup, rows, cols, vals, off, cur, epk);
    k_agg<<<(NN + 3) / 4, 256, 0, stream>>>(sup, off, epk, bias, flags, out);
}

// Round 3
// 400.904 us; speedup vs baseline: 1.2809x; 1.2809x over previous
//
#include <hip/hip_runtime.h>
#include <hip/hip_bf16.h>

// Problem constants
#define BB 4
#define NN 50000
#define DIN 128
#define DOUT 128
#define EE 800000
#define TOTROWS (BB * NN)   // 200000
#define LDA 136             // padded LDS row stride (u16): 272B = 17*16B

#define NGB ((TOTROWS + 127) / 128)        // 1563 gemm blocks
#define NHB ((EE + 255) / 256)             // 3125 hist/scatter blocks
#define CHUNK 1024
#define NCHUNK ((NN + CHUNK - 1) / CHUNK)  // 49
#define NPB 64                             // prep blocks (64*256 == 128*128)
#define PAD8(x) (((x) + 7) & ~7)
#define EPK_CAP (EE + 8 * NN)              // padded-CSR capacity (1.2M edges)
#define NAB (NN / 4)                       // 12500 agg blocks per feature pass

typedef unsigned short u16;
typedef unsigned int u32;

using shortx8 = __attribute__((ext_vector_type(8))) short;
using ushortx4 = __attribute__((ext_vector_type(4))) unsigned short;
using ushortx8 = __attribute__((ext_vector_type(8))) unsigned short;
using floatx4 = __attribute__((ext_vector_type(4))) float;

__device__ __forceinline__ float b2f(u16 u) {
    u32 x = ((u32)u) << 16;
    float f;
    __builtin_memcpy(&f, &x, 4);
    return f;
}

__device__ __forceinline__ u16 f2b(float f) {
    u32 x;
    __builtin_memcpy(&x, &f, 4);
    u32 r = x + 0x7fffu + ((x >> 16) & 1u);   // RNE
    return (u16)(r >> 16);
}

// ---------------------------------------------------------------------------
// K1: block 0 = dtype detector; blocks 1.. = degree histogram.
// flags[i] = 1 if fp32-stored, 0 if bf16-stored.
// ---------------------------------------------------------------------------
__global__ __launch_bounds__(256)
void k1_detect_hist(const u16* __restrict__ X, const u16* __restrict__ W,
                    const u16* __restrict__ Bs, const u16* __restrict__ V,
                    int nx, int nw, int nb, int nv, int* __restrict__ flags,
                    const int* __restrict__ rows, int* __restrict__ deg) {
    if (blockIdx.x == 0) {
        __shared__ int cnt[4];
        const int t = threadIdx.x;
        const int w = t >> 6;
        const int l = t & 63;
        if (t < 4) cnt[t] = 0;
        __syncthreads();
        const u16* p = (w == 0) ? X : (w == 1) ? W : (w == 2) ? Bs : V;
        const int n  = (w == 0) ? nx : (w == 1) ? nw : (w == 2) ? nb : nv;
        int bad = 0;
        for (int k = 0; k < 4; ++k) {
            unsigned idx = 2u * (unsigned)(((unsigned long long)(l * 4 + k) *
                                            (unsigned)(n >> 1)) >> 8);
            u16 s = p[idx];
            unsigned e = (s >> 7) & 0xFF;
            bool ok = ((s & 0x7FFF) == 0) || (e >= 90 && e <= 141);
            bad += ok ? 0 : 1;
        }
        atomicAdd(&cnt[w], bad);
        __syncthreads();
        if (l == 0) flags[w] = (cnt[w] >= 77) ? 1 : 0;   // >=30% implausible
    } else {
        int e = (int)(blockIdx.x - 1) * 256 + threadIdx.x;
        if (e < EE) atomicAdd(&deg[rows[e]], 1);
    }
}

// ---------------------------------------------------------------------------
// K2: blocks 0..NCHUNK-1 = scan reduce over PADDED degrees;
//     blocks NCHUNK..    = Wt[f*128+k] = bf16(W[k*128+f]) transpose+convert.
// ---------------------------------------------------------------------------
__global__ __launch_bounds__(256)
void k2_scanred_prep(const int* __restrict__ deg, int* __restrict__ bsum,
                     const void* __restrict__ Wv, const int* __restrict__ flags,
                     u16* __restrict__ Wt) {
    if (blockIdx.x < NCHUNK) {
        __shared__ int sh[256];
        int t = threadIdx.x, blk = blockIdx.x;
        int base = blk * CHUNK + t * 4;
        int s = 0;
#pragma unroll
        for (int i = 0; i < 4; ++i) {
            int idx = base + i;
            if (idx < NN) s += PAD8(deg[idx]);
        }
        sh[t] = s;
        __syncthreads();
        for (int d = 128; d > 0; d >>= 1) {
            if (t < d) sh[t] += sh[t + d];
            __syncthreads();
        }
        if (t == 0) bsum[blk] = sh[0];
    } else {
        int t = (int)(blockIdx.x - NCHUNK) * 256 + threadIdx.x;
        if (t < DIN * DOUT) {
            int f = t >> 7, k = t & 127;
            size_t src = (size_t)k * DOUT + f;
            Wt[t] = flags[1] ? f2b(((const float*)Wv)[src]) : ((const u16*)Wv)[src];
        }
    }
}

__global__ __launch_bounds__(64)
void k_scan_base(const int* __restrict__ bsum, int* __restrict__ bbase,
                 int* __restrict__ off) {
    int l = threadIdx.x;
    int orig = (l < NCHUNK) ? bsum[l] : 0;
    int v = orig;
    for (int d = 1; d < 64; d <<= 1) {
        int x = __shfl_up(v, d);
        if (l >= d) v += x;
    }
    if (l < NCHUNK) bbase[l] = v - orig;     // exclusive
    if (l == NCHUNK - 1) off[NN] = v;        // == padded E
}

__global__ __launch_bounds__(256)
void k_scan_chunk(const int* __restrict__ deg, const int* __restrict__ bbase,
                  int* __restrict__ off) {
    __shared__ int sh[256];
    int t = threadIdx.x;
    int blk = blockIdx.x;
    int base = blk * CHUNK + t * 4;
    int v[4];
    int tsum = 0;
#pragma unroll
    for (int i = 0; i < 4; ++i) {
        int idx = base + i;
        v[i] = (idx < NN) ? PAD8(deg[idx]) : 0;
        tsum += v[i];
    }
    sh[t] = tsum;
    __syncthreads();
    for (int d = 1; d < 256; d <<= 1) {
        int x = (t >= d) ? sh[t - d] : 0;
        __syncthreads();
        sh[t] += x;
        __syncthreads();
    }
    int run = sh[t] - tsum + bbase[blk];
#pragma unroll
    for (int i = 0; i < 4; ++i) {
        int idx = base + i;
        if (idx < NN) off[idx] = run;
        run += v[i];
    }
}

// ---------------------------------------------------------------------------
// K5: blocks 0..NGB-1 = GEMM sup[(n*B+b)*128+f] = bf16(X[b*N+n,:] @ W);
//     blocks NGB..    = edge scatter into padded CSR (overlapped with GEMM).
// Pad slots in epk stay {0,0} from the memset -> contribute 0 to aggregation.
// ---------------------------------------------------------------------------
__global__ __launch_bounds__(256, 3)
void k5_gemm_scatter(const void* __restrict__ Xv, const u16* __restrict__ Wt,
                     const int* __restrict__ flags, u16* __restrict__ sup,
                     const int* __restrict__ rows, const int* __restrict__ cols,
                     const void* __restrict__ valsv, const int* __restrict__ off,
                     int* __restrict__ cur, int2* __restrict__ epk) {
    if (blockIdx.x >= NGB) {
        // ---- scatter branch (no syncthreads before this return) ----
        int e = (int)(blockIdx.x - NGB) * 256 + threadIdx.x;
        if (e < EE) {
            int vf32 = flags[3];
            float v = vf32 ? ((const float*)valsv)[e]
                           : b2f(((const u16*)valsv)[e]);
            int r = rows[e];
            int p = off[r] + atomicAdd(&cur[r], 1);
            epk[p] = make_int2(cols[e], __float_as_int(v));
        }
        return;
    }

    // ---- GEMM branch ----
    __shared__ u16 lA[128 * LDA];   // 34 KB

    const int xf32 = flags[0];
    const int tid = threadIdx.x;
    const int wid = tid >> 6;
    const int l   = tid & 63;
    const long rowBase = (long)blockIdx.x * 128;

    if (xf32) {
        const float* Xf = (const float*)Xv;
#pragma unroll
        for (int i = 0; i < 16; ++i) {
            int elem = i * 1024 + tid * 4;   // row*128 + col
            int row = elem >> 7, col = elem & 127;
            long gRow = rowBase + row;
            ushortx4 w4 = (ushortx4){0, 0, 0, 0};
            if (gRow < TOTROWS) {
                float4 v = *(const float4*)(Xf + gRow * DIN + col);
                w4[0] = f2b(v.x); w4[1] = f2b(v.y);
                w4[2] = f2b(v.z); w4[3] = f2b(v.w);
            }
            *(ushortx4*)&lA[row * LDA + col] = w4;
        }
    } else {
        const u16* X16 = (const u16*)Xv;
#pragma unroll
        for (int i = 0; i < 8; ++i) {
            int elem = i * 2048 + tid * 8;
            int row = elem >> 7, col = elem & 127;
            long gRow = rowBase + row;
            ushortx8 w8 = (ushortx8){0, 0, 0, 0, 0, 0, 0, 0};
            if (gRow < TOTROWS)
                w8 = *(const ushortx8*)(X16 + gRow * DIN + col);
            *(ushortx8*)&lA[row * LDA + col] = w8;
        }
    }

    const int wx = wid & 1;        // col half
    const int wy = wid >> 1;       // row half
    const int q8 = (l >> 4) * 8;   // k sub-offset
    const int lm = l & 15;

    shortx8 bf[16];
#pragma unroll
    for (int nt = 0; nt < 4; ++nt) {
        const size_t Frow = (size_t)(wx * 64 + nt * 16 + lm) * DIN;
#pragma unroll
        for (int c = 0; c < 4; ++c)
            bf[nt * 4 + c] = *(const shortx8*)(Wt + Frow + 32 * c + q8);
    }

    floatx4 acc[4][4];
#pragma unroll
    for (int mt = 0; mt < 4; ++mt)
#pragma unroll
        for (int nt = 0; nt < 4; ++nt)
            acc[mt][nt] = (floatx4){0.f, 0.f, 0.f, 0.f};

    __syncthreads();

    for (int c = 0; c < 4; ++c) {
        shortx8 af[4];
#pragma unroll
        for (int mt = 0; mt < 4; ++mt)
            af[mt] = *(const shortx8*)
                &lA[(size_t)(wy * 64 + mt * 16 + lm) * LDA + 32 * c + q8];
#pragma unroll
        for (int mt = 0; mt < 4; ++mt)
#pragma unroll
            for (int nt = 0; nt < 4; ++nt)
                acc[mt][nt] = __builtin_amdgcn_mfma_f32_16x16x32_bf16(
                    af[mt], bf[nt * 4 + c], acc[mt][nt], 0, 0, 0);
    }

    __syncthreads();   // all A-frag reads complete before overwrite
#pragma unroll
    for (int mt = 0; mt < 4; ++mt) {
#pragma unroll
        for (int reg = 0; reg < 4; ++reg) {
            int row = wy * 64 + mt * 16 + (l >> 4) * 4 + reg;
#pragma unroll
            for (int nt = 0; nt < 4; ++nt)
                lA[row * LDA + wx * 64 + nt * 16 + lm] = f2b(acc[mt][nt][reg]);
        }
    }
    __syncthreads();

#pragma unroll
    for (int i = 0; i < 8; ++i) {
        int elem = i * 2048 + tid * 8;
        int row = elem >> 7, col = elem & 127;
        long R = rowBase + row;
        if (R < TOTROWS) {
            int b = (int)(R / NN);
            int n = (int)(R % NN);
            ushortx8 v = *(const ushortx8*)&lA[row * LDA + col];
            *(ushortx8*)(sup + ((size_t)n * BB + b) * DOUT + col) = v;
        }
    }
}

// ---------------------------------------------------------------------------
// K6: aggregation, 2 feature passes. Pass p covers feats [p*64, p*64+64);
// per-pass gather footprint = 25.6 MB (vs 51.2) to raise per-XCD L2 hit rate.
// One wave per node per pass; lane covers (b = l>>4, f = p*64 + (l&15)*4),
// 8B gathers (each 16-lane group reads one 128B line). Descriptors are
// loaded once per 64-edge chunk (coalesced, nontemporal so the epk stream
// doesn't evict sup in L2) and broadcast via readlane into SGPRs.
// ---------------------------------------------------------------------------
__global__ __launch_bounds__(256)
void k_agg(const u16* __restrict__ sup, const int* __restrict__ off,
           const int2* __restrict__ epk, const void* __restrict__ biasv,
           const int* __restrict__ flags, float* __restrict__ out) {
    int blk = blockIdx.x;
    const int pass = (blk >= NAB) ? 1 : 0;
    if (pass) blk -= NAB;
    const int wid = threadIdx.x >> 6;
    const int l   = threadIdx.x & 63;
    const int n = blk * 4 + wid;

    const int p0 = __builtin_amdgcn_readfirstlane(off[n]);
    const int p1 = __builtin_amdgcn_readfirstlane(off[n + 1]);

    float acc[4] = {0.f, 0.f, 0.f, 0.f};
    const int b  = l >> 4;
    const int f0 = pass * 64 + (l & 15) * 4;
    const int lofs = b * 128 + f0;   // u16 elements within the 512-elem node row

    for (int pb = p0; pb < p1; pb += 64) {
        const int cnt = min(64, p1 - pb);   // multiple of 8 (padded degrees)
        int2 d = make_int2(0, 0);
        if (l < cnt) {
            long long dv = __builtin_nontemporal_load(
                (const long long*)(epk + pb + l));
            d.x = (int)(dv & 0xFFFFFFFFLL);
            d.y = (int)(dv >> 32);
        }
        for (int j = 0; j < cnt; j += 8) {
            int   cs[8];
            float vs[8];
#pragma unroll
            for (int q = 0; q < 8; ++q) {
                cs[q] = __builtin_amdgcn_readlane(d.x, j + q);
                vs[q] = __int_as_float(__builtin_amdgcn_readlane(d.y, j + q));
            }
            ushortx4 sv[8];
#pragma unroll
            for (int q = 0; q < 8; ++q)
                sv[q] = *(const ushortx4*)(sup + (size_t)cs[q] * 512 + lofs);
#pragma unroll
            for (int q = 0; q < 8; ++q)
#pragma unroll
                for (int t = 0; t < 4; ++t)
                    acc[t] += vs[q] * b2f(sv[q][t]);
        }
    }

    float bb[4];
    if (flags[2]) {
        float4 bv = *(const float4*)((const float*)biasv + f0);
        bb[0] = bv.x; bb[1] = bv.y; bb[2] = bv.z; bb[3] = bv.w;
    } else {
        ushortx4 bv = *(const ushortx4*)((const u16*)biasv + f0);
#pragma unroll
        for (int t = 0; t < 4; ++t) bb[t] = b2f(bv[t]);
    }

    floatx4 r;
#pragma unroll
    for (int t = 0; t < 4; ++t) r[t] = fmaxf(acc[t] + bb[t], 0.f);

    float* op = out + ((size_t)b * NN + n) * DOUT + f0;
    __builtin_nontemporal_store(r, (floatx4*)op);
}

// ---------------------------------------------------------------------------
extern "C" void kernel_launch(void* const* d_in, const int* in_sizes, int n_in,
                              void* d_out, int out_size, void* d_ws, size_t ws_size,
                              hipStream_t stream) {
    const void* X    = d_in[0];
    const void* W    = d_in[1];
    const void* bias = d_in[2];
    const void* vals = d_in[3];
    const int* rows  = (const int*)d_in[4];
    const int* cols  = (const int*)d_in[5];
    float* out = (float*)d_out;

    char* base = (char*)d_ws;
    size_t o = 0;
    int* flags = (int*)(base + o); o += 64;
    int* deg = (int*)(base + o); o += (size_t)NN * 4;
    int* cur = (int*)(base + o); o += (size_t)NN * 4;    // deg+cur contiguous
    o = (o + 255) & ~(size_t)255;
    int* bsum  = (int*)(base + o); o += 64 * 4;
    int* bbase = (int*)(base + o); o += 64 * 4;
    o = (o + 255) & ~(size_t)255;
    u16* Wt = (u16*)(base + o); o += (size_t)DIN * DOUT * 2;
    o = (o + 255) & ~(size_t)255;
    int* off = (int*)(base + o); o += (size_t)(NN + 1) * 4;
    o = (o + 255) & ~(size_t)255;
    int2* epk = (int2*)(base + o); o += (size_t)EPK_CAP * 8;
    o = (o + 255) & ~(size_t)255;
    u16* sup = (u16*)(base + o); o += (size_t)BB * NN * DOUT * 2;
    (void)ws_size;

    hipMemsetAsync(deg, 0, (size_t)2 * NN * 4, stream);      // deg + cur
    hipMemsetAsync(epk, 0, (size_t)EPK_CAP * 8, stream);     // pad slots = 0

    k1_detect_hist<<<1 + NHB, 256, 0, stream>>>(
        (const u16*)X, (const u16*)W, (const u16*)bias, (const u16*)vals,
        in_sizes[0], in_sizes[1], in_sizes[2], in_sizes[3], flags, rows, deg);
    k2_scanred_prep<<<NCHUNK + NPB, 256, 0, stream>>>(deg, bsum, W, flags, Wt);
    k_scan_base<<<1, 64, 0, stream>>>(bsum, bbase, off);
    k_scan_chunk<<<NCHUNK, 256, 0, stream>>>(deg, bbase, off);
    k5_gemm_scatter<<<NGB + NHB, 256, 0, stream>>>(
        X, Wt, flags, sup, rows, cols, vals, off, cur, epk);
    k_agg<<<2 * NAB, 256, 0, stream>>>(sup, off, epk, bias, flags, out);
}